// Round 3
// baseline (818.677 us; speedup 1.0000x reference)
//
#include <hip/hip_runtime.h>
#include <hip/hip_bf16.h>

typedef __attribute__((ext_vector_type(8))) short bf16x8;
typedef __attribute__((ext_vector_type(4))) float f32x4;
typedef unsigned short u16;
typedef unsigned int u32;

__device__ __forceinline__ u32 bf16_rne(float f) {
  u32 u = __float_as_uint(f);
  return (u + 0x7FFFu + ((u >> 16) & 1u)) >> 16;
}
__device__ __forceinline__ float bf16_val(u32 b) { return __uint_as_float(b << 16); }

__device__ __forceinline__ void g2l16(const u16* g, void* l) {
  __builtin_amdgcn_global_load_lds(
      (const __attribute__((address_space(1))) u32*)g,
      (__attribute__((address_space(3))) u32*)l, 16, 0, 0);
}

// ---- split fp32 array into bf16 hi/lo (no transpose) ----
__global__ void split_arr(const float* __restrict__ in,
                          u16* __restrict__ hi, u16* __restrict__ lo, int n4) {
  int i = blockIdx.x * 256 + threadIdx.x;
  if (i >= n4) return;
  float4 v = ((const float4*)in)[i];
  u32 h0 = bf16_rne(v.x), h1 = bf16_rne(v.y), h2 = bf16_rne(v.z), h3 = bf16_rne(v.w);
  u32 l0 = bf16_rne(v.x - bf16_val(h0));
  u32 l1 = bf16_rne(v.y - bf16_val(h1));
  u32 l2 = bf16_rne(v.z - bf16_val(h2));
  u32 l3 = bf16_rne(v.w - bf16_val(h3));
  ushort4 hv; hv.x = (u16)h0; hv.y = (u16)h1; hv.z = (u16)h2; hv.w = (u16)h3;
  ushort4 lv; lv.x = (u16)l0; lv.y = (u16)l1; lv.z = (u16)l2; lv.w = (u16)l3;
  ((ushort4*)hi)[i] = hv;
  ((ushort4*)lo)[i] = lv;
}

// ---- transpose each 256x256 fp32 slice and split into bf16 hi/lo arrays ----
__global__ void split_transpose256(const float* __restrict__ in,
                                   u16* __restrict__ hi, u16* __restrict__ lo) {
  __shared__ float tile[32][33];
  const size_t off = (size_t)blockIdx.z * 65536;
  const int tx = threadIdx.x, ty = threadIdx.y;
#pragma unroll
  for (int i = 0; i < 4; ++i) {
    int y = blockIdx.y * 32 + ty + i * 8;
    int x = blockIdx.x * 32 + tx;
    tile[ty + i * 8][tx] = in[off + (size_t)y * 256 + x];
  }
  __syncthreads();
#pragma unroll
  for (int i = 0; i < 4; ++i) {
    float v = tile[tx][ty + i * 8];
    u32 hb = bf16_rne(v);
    u32 lb = bf16_rne(v - bf16_val(hb));
    size_t idx = off + (size_t)(blockIdx.x * 32 + ty + i * 8) * 256 + blockIdx.y * 32 + tx;
    hi[idx] = (u16)hb;
    lo[idx] = (u16)lb;
  }
}

// ---------------- fused priors-GEMM (split-bf16) + dynamic routing ----------------
// 512 threads = 8 waves; wave w owns e-slice [w*32, w*32+32).
// P[b,e]: row b = mt*16 + q*4 + r, col e = w*32 + ct*16 + li.
template <int R>
__global__ __launch_bounds__(512, 4) void caps_route(
    const u16* __restrict__ Ahi_g,   // [64][R][256] bf16-hi
    const u16* __restrict__ Alo_g,   // [64][R][256] bf16-lo
    const u16* __restrict__ Whi,     // [KN][256][256] (transposed [e][d])
    const u16* __restrict__ Wlo,
    u16* __restrict__ o1hi, u16* __restrict__ o1lo,   // stage1 out (split)
    float* __restrict__ outp,                          // stage2 out
    int KN, int stage) {
  constexpr int MT = R / 16;
  __shared__ u16 Bhi[256 * 32];    // unpadded 64 B rows (global_load_lds layout)
  __shared__ u16 Blo[256 * 32];
  __shared__ __align__(16) float wlog[8][R];
  __shared__ float logits[R];
  __shared__ __align__(16) float probs[R];
  __shared__ float sqpart[8];

  const int tid = threadIdx.x;
  const int w = tid >> 6, lane = tid & 63, q = lane >> 4, li = lane & 15;
  const int kk = blockIdx.x >> 6;   // weight slice (h or c)
  const int a  = blockIdx.x & 63;

  const u16* ArH = Ahi_g + (size_t)a * R * 256;
  const u16* ArL = Alo_g + (size_t)a * R * 256;
  const u16* WhR = Whi + (size_t)kk * 65536;
  const u16* WlR = Wlo + (size_t)kk * 65536;

  f32x4 acc[MT][2] = {};

  // ---- GEMM: P = A (R x 256) @ W[kk] (256 x 256), split-bf16 3-MFMA ----
  for (int ks = 0; ks < 8; ++ks) {
    const int k0 = ks * 32;
    // async B staging: wave w stages rows [w*32, w*32+32), lane-contiguous 16B
#pragma unroll
    for (int j = 0; j < 2; ++j) {
      int e = w * 32 + j * 16 + (lane >> 2);
      int p = lane & 3;
      g2l16(WhR + e * 256 + k0 + p * 8, (char*)Bhi + e * 64 + p * 16);
      g2l16(WlR + e * 256 + k0 + p * 8, (char*)Blo + e * 64 + p * 16);
    }
    __syncthreads();   // drains vmcnt (DMA) before reads
    bf16x8 bh[2], bl[2];
#pragma unroll
    for (int ct = 0; ct < 2; ++ct) {
      int e = w * 32 + ct * 16 + li;
      bh[ct] = *(const bf16x8*)((const char*)Bhi + e * 64 + q * 16);
      bl[ct] = *(const bf16x8*)((const char*)Blo + e * 64 + q * 16);
    }
#pragma unroll
    for (int mt = 0; mt < MT; ++mt) {
      int row = mt * 16 + li;
      bf16x8 ah = *(const bf16x8*)(ArH + row * 256 + k0 + q * 8);
      bf16x8 al = *(const bf16x8*)(ArL + row * 256 + k0 + q * 8);
#pragma unroll
      for (int ct = 0; ct < 2; ++ct) {
        acc[mt][ct] = __builtin_amdgcn_mfma_f32_16x16x32_bf16(al, bh[ct], acc[mt][ct], 0, 0, 0);
        acc[mt][ct] = __builtin_amdgcn_mfma_f32_16x16x32_bf16(ah, bl[ct], acc[mt][ct], 0, 0, 0);
        acc[mt][ct] = __builtin_amdgcn_mfma_f32_16x16x32_bf16(ah, bh[ct], acc[mt][ct], 0, 0, 0);
      }
    }
    __syncthreads();
  }

  // ---- dynamic routing (3 iterations) on register-resident P ----
  const float invR = 1.0f / R;
  float v[2];

  for (int iter = 0; iter < 3; ++iter) {
    // s[e] = sum_b probs[b] * P[b,e]
    float s[2];
#pragma unroll
    for (int ct = 0; ct < 2; ++ct) {
      float t = 0.f;
#pragma unroll
      for (int mt = 0; mt < MT; ++mt) {
        float4 p4;
        if (iter == 0) { p4.x = invR; p4.y = invR; p4.z = invR; p4.w = invR; }
        else           { p4 = *(const float4*)&probs[mt * 16 + q * 4]; }
        t += p4.x * acc[mt][ct][0];
        t += p4.y * acc[mt][ct][1];
        t += p4.z * acc[mt][ct][2];
        t += p4.w * acc[mt][ct][3];
      }
      t += __shfl_xor(t, 16);
      t += __shfl_xor(t, 32);
      s[ct] = t;
    }
    // squash
    float ss = s[0] * s[0] + s[1] * s[1];
    ss += __shfl_xor(ss, 1);
    ss += __shfl_xor(ss, 2);
    ss += __shfl_xor(ss, 4);
    ss += __shfl_xor(ss, 8);
    if (lane == 0) sqpart[w] = ss;
    __syncthreads();
    float sq = sqpart[0] + sqpart[1] + sqpart[2] + sqpart[3] +
               sqpart[4] + sqpart[5] + sqpart[6] + sqpart[7];
    float scale = (sq > 0.f) ? sq / ((1.0f + sq) * sqrtf(sq)) : 0.f;
    v[0] = s[0] * scale;
    v[1] = s[1] * scale;

    if (iter < 2) {
      // logits[b] += sum_e P[b,e] * v[e]
#pragma unroll
      for (int mt = 0; mt < MT; ++mt) {
        float p0, p1, p2, p3;
        {
          float t = acc[mt][0][0] * v[0] + acc[mt][1][0] * v[1];
          t += __shfl_xor(t, 1); t += __shfl_xor(t, 2);
          t += __shfl_xor(t, 4); t += __shfl_xor(t, 8);
          p0 = t;
        }
        {
          float t = acc[mt][0][1] * v[0] + acc[mt][1][1] * v[1];
          t += __shfl_xor(t, 1); t += __shfl_xor(t, 2);
          t += __shfl_xor(t, 4); t += __shfl_xor(t, 8);
          p1 = t;
        }
        {
          float t = acc[mt][0][2] * v[0] + acc[mt][1][2] * v[1];
          t += __shfl_xor(t, 1); t += __shfl_xor(t, 2);
          t += __shfl_xor(t, 4); t += __shfl_xor(t, 8);
          p2 = t;
        }
        {
          float t = acc[mt][0][3] * v[0] + acc[mt][1][3] * v[1];
          t += __shfl_xor(t, 1); t += __shfl_xor(t, 2);
          t += __shfl_xor(t, 4); t += __shfl_xor(t, 8);
          p3 = t;
        }
        if (li == 0)
          *(float4*)&wlog[w][mt * 16 + q * 4] = make_float4(p0, p1, p2, p3);
      }
      __syncthreads();
      if (tid < R) {
        float l = (iter == 0 ? 0.f : logits[tid]);
        l += wlog[0][tid] + wlog[1][tid] + wlog[2][tid] + wlog[3][tid] +
             wlog[4][tid] + wlog[5][tid] + wlog[6][tid] + wlog[7][tid];
        logits[tid] = l;
      }
      __syncthreads();
      if (w == 0) {  // softmax over R logits, wave 0
        float l0 = logits[lane];
        float l1 = (R == 128) ? logits[lane + 64] : -3.0e38f;
        float m = fmaxf(l0, l1);
#pragma unroll
        for (int d2 = 1; d2 < 64; d2 <<= 1) m = fmaxf(m, __shfl_xor(m, d2));
        float e0 = expf(l0 - m);
        float e1 = (R == 128) ? expf(l1 - m) : 0.f;
        float zz = e0 + e1;
#pragma unroll
        for (int d2 = 1; d2 < 64; d2 <<= 1) zz += __shfl_xor(zz, d2);
        float inv = 1.0f / zz;
        probs[lane] = e0 * inv;
        if (R == 128) probs[lane + 64] = e1 * inv;
      }
      __syncthreads();
    }
  }

  // ---- epilogue. stage1 -> split out1[a][kk][e]; stage2 -> fp32 out[kk][a][e] ----
  if (q == 0) {
    if (stage == 1) {
      size_t ob = ((size_t)a * KN + kk) * 256;
#pragma unroll
      for (int ct = 0; ct < 2; ++ct) {
        int e = w * 32 + ct * 16 + li;
        u32 hb = bf16_rne(v[ct]);
        u32 lb = bf16_rne(v[ct] - bf16_val(hb));
        o1hi[ob + e] = (u16)hb;
        o1lo[ob + e] = (u16)lb;
      }
    } else {
      size_t ob = ((size_t)kk * 64 + a) * 256;
#pragma unroll
      for (int ct = 0; ct < 2; ++ct) {
        int e = w * 32 + ct * 16 + li;
        outp[ob + e] = v[ct];
      }
    }
  }
}

extern "C" void kernel_launch(void* const* d_in, const int* in_sizes, int n_in,
                              void* d_out, int out_size, void* d_ws, size_t ws_size,
                              hipStream_t stream) {
  const float* x  = (const float*)d_in[0];   // [64][128][256]
  const float* w1 = (const float*)d_in[1];   // [64][256][256]
  const float* wc = (const float*)d_in[2];   // [32][256][256]
  float* out = (float*)d_out;                // [32][64][256]

  char* ws = (char*)d_ws;
  u16* w1hi = (u16*)(ws);                    // 8 MB
  u16* w1lo = (u16*)(ws + (8u << 20));       // 8 MB
  u16* wchi = (u16*)(ws + (16u << 20));      // 4 MB
  u16* wclo = (u16*)(ws + (20u << 20));      // 4 MB
  u16* xhi  = (u16*)(ws + (24u << 20));      // 4 MB
  u16* xlo  = (u16*)(ws + (28u << 20));      // 4 MB
  u16* o1hi = (u16*)(ws + (32u << 20));      // 2 MB
  u16* o1lo = (u16*)(ws + (34u << 20));      // 2 MB

  split_arr<<<2048, 256, 0, stream>>>(x, xhi, xlo, 524288);
  split_transpose256<<<dim3(8, 8, 64), dim3(32, 8), 0, stream>>>(w1, w1hi, w1lo);
  split_transpose256<<<dim3(8, 8, 32), dim3(32, 8), 0, stream>>>(wc, wchi, wclo);
  caps_route<128><<<64 * 64, 512, 0, stream>>>(xhi, xlo, w1hi, w1lo, o1hi, o1lo, nullptr, 64, 1);
  caps_route<64><<<32 * 64, 512, 0, stream>>>(o1hi, o1lo, wchi, wclo, nullptr, nullptr, out, 32, 2);
}

// Round 4
// 407.328 us; speedup vs baseline: 2.0099x; 2.0099x over previous
//
#include <hip/hip_runtime.h>
#include <hip/hip_bf16.h>

typedef __attribute__((ext_vector_type(8))) short bf16x8;
typedef __attribute__((ext_vector_type(4))) float f32x4;
typedef unsigned short u16;
typedef unsigned int u32;

__device__ __forceinline__ u32 bf16_rne(float f) {
  u32 u = __float_as_uint(f);
  return (u + 0x7FFFu + ((u >> 16) & 1u)) >> 16;
}
__device__ __forceinline__ float bf16_val(u32 b) { return __uint_as_float(b << 16); }

__device__ __forceinline__ void g2l16(const u16* g, u16* l) {
  __builtin_amdgcn_global_load_lds(
      (const __attribute__((address_space(1))) u32*)g,
      (__attribute__((address_space(3))) u32*)l, 16, 0, 0);
}

// ---- split fp32 array into bf16 hi/lo (no transpose) ----
__global__ void split_arr(const float* __restrict__ in,
                          u16* __restrict__ hi, u16* __restrict__ lo, int n4) {
  int i = blockIdx.x * 256 + threadIdx.x;
  if (i >= n4) return;
  float4 v = ((const float4*)in)[i];
  u32 h0 = bf16_rne(v.x), h1 = bf16_rne(v.y), h2 = bf16_rne(v.z), h3 = bf16_rne(v.w);
  u32 l0 = bf16_rne(v.x - bf16_val(h0));
  u32 l1 = bf16_rne(v.y - bf16_val(h1));
  u32 l2 = bf16_rne(v.z - bf16_val(h2));
  u32 l3 = bf16_rne(v.w - bf16_val(h3));
  ushort4 hv; hv.x = (u16)h0; hv.y = (u16)h1; hv.z = (u16)h2; hv.w = (u16)h3;
  ushort4 lv; lv.x = (u16)l0; lv.y = (u16)l1; lv.z = (u16)l2; lv.w = (u16)l3;
  ((ushort4*)hi)[i] = hv;
  ((ushort4*)lo)[i] = lv;
}

// ---- transpose each 256x256 fp32 slice and split into bf16 hi/lo arrays ----
__global__ void split_transpose256(const float* __restrict__ in,
                                   u16* __restrict__ hi, u16* __restrict__ lo) {
  __shared__ float tile[32][33];
  const size_t off = (size_t)blockIdx.z * 65536;
  const int tx = threadIdx.x, ty = threadIdx.y;
#pragma unroll
  for (int i = 0; i < 4; ++i) {
    int y = blockIdx.y * 32 + ty + i * 8;
    int x = blockIdx.x * 32 + tx;
    tile[ty + i * 8][tx] = in[off + (size_t)y * 256 + x];
  }
  __syncthreads();
#pragma unroll
  for (int i = 0; i < 4; ++i) {
    float v = tile[tx][ty + i * 8];
    u32 hb = bf16_rne(v);
    u32 lb = bf16_rne(v - bf16_val(hb));
    size_t idx = off + (size_t)(blockIdx.x * 32 + ty + i * 8) * 256 + blockIdx.y * 32 + tx;
    hi[idx] = (u16)hb;
    lo[idx] = (u16)lb;
  }
}

// ---------------- fused priors-GEMM (split-bf16) + dynamic routing ----------------
// 512 threads = 8 waves, wave grid mg(2) x eg(4).
// Wave (mg,eg) owns P rows [mg*R/2 .. +R/2) x cols [eg*64 .. +64).
// P[b,e]: b = mg*(R/2) + mt*16 + q*4 + r, e = eg*64 + ct*16 + li.
template <int R>
__global__ __launch_bounds__(512, 4) void caps_route(
    const u16* __restrict__ Ahi_g,   // [64][R][256] bf16-hi
    const u16* __restrict__ Alo_g,   // [64][R][256] bf16-lo
    const u16* __restrict__ Whi,     // [KN][256][256] (transposed [e][d])
    const u16* __restrict__ Wlo,
    u16* __restrict__ o1hi, u16* __restrict__ o1lo,   // stage1 out (split)
    float* __restrict__ outp,                          // stage2 out
    int KN, int stage) {
  constexpr int MTW = R / 32;        // m-tiles per wave
  constexpr int NA = R / 16;         // A hi chunks (16 rows x 64 B each)
  constexpr int NTOT = 2 * NA + 32;  // + B hi/lo chunks
  __shared__ u16 BUF[NTOT * 512];    // [Ahi | Alo | Bhi | Blo], rows stride 32 u16
  __shared__ __align__(16) float smat[2][256];
  __shared__ __align__(16) float wlog[4][R];
  __shared__ float logits[R];
  __shared__ __align__(16) float probs[R];
  __shared__ float sqpart[4];

  u16* Ahi = BUF;
  u16* Alo = BUF + NA * 512;
  u16* Bhi = BUF + 2 * NA * 512;
  u16* Blo = BUF + 2 * NA * 512 + 8192;

  const int tid = threadIdx.x;
  const int w = tid >> 6, lane = tid & 63, q = lane >> 4, li = lane & 15;
  const int mg = w >> 2, eg = w & 3;
  const int kk = blockIdx.x >> 6;   // weight slice (h or c)
  const int a  = blockIdx.x & 63;

  const u16* ArH = Ahi_g + (size_t)a * R * 256;
  const u16* ArL = Alo_g + (size_t)a * R * 256;
  const u16* WhR = Whi + (size_t)kk * 65536;
  const u16* WlR = Wlo + (size_t)kk * 65536;

  f32x4 acc[MTW][4] = {};

  const int sub = lane >> 2, p = lane & 3;
  const int laneoff = sub * 256 + p * 8;   // global per-lane offset within a chunk

  // ---- GEMM: P = A (R x 256) @ W[kk] (256 x 256), split-bf16 3-MFMA ----
  for (int ks = 0; ks < 8; ++ks) {
    const int k0 = ks * 32;
    // async DMA staging: chunk c = 16 rows x 64 B
#pragma unroll
    for (int c = w; c < NTOT; c += 8) {
      const u16* g;
      if (c < NA)              g = ArH + (c) * 4096;
      else if (c < 2 * NA)     g = ArL + (c - NA) * 4096;
      else if (c < 2 * NA + 16) g = WhR + (c - 2 * NA) * 4096;
      else                     g = WlR + (c - 2 * NA - 16) * 4096;
      g2l16(g + laneoff + k0, BUF + c * 512 + lane * 8);
    }
    __syncthreads();   // drains DMA (vmcnt) before reads
    bf16x8 bh[4], bl[4];
#pragma unroll
    for (int ct = 0; ct < 4; ++ct) {
      int e = eg * 64 + ct * 16 + li;
      bh[ct] = *(const bf16x8*)(Bhi + e * 32 + q * 8);
      bl[ct] = *(const bf16x8*)(Blo + e * 32 + q * 8);
    }
#pragma unroll
    for (int mt = 0; mt < MTW; ++mt) {
      int row = mg * (R / 2) + mt * 16 + li;
      bf16x8 ah = *(const bf16x8*)(Ahi + row * 32 + q * 8);
      bf16x8 al = *(const bf16x8*)(Alo + row * 32 + q * 8);
#pragma unroll
      for (int ct = 0; ct < 4; ++ct) {
        acc[mt][ct] = __builtin_amdgcn_mfma_f32_16x16x32_bf16(al, bh[ct], acc[mt][ct], 0, 0, 0);
        acc[mt][ct] = __builtin_amdgcn_mfma_f32_16x16x32_bf16(ah, bl[ct], acc[mt][ct], 0, 0, 0);
        acc[mt][ct] = __builtin_amdgcn_mfma_f32_16x16x32_bf16(ah, bh[ct], acc[mt][ct], 0, 0, 0);
      }
    }
    __syncthreads();
  }

  // ---- dynamic routing (3 iterations) on register-resident P ----
  const float invR = 1.0f / R;
  float v[4];

  for (int iter = 0; iter < 3; ++iter) {
    // s[e] = sum_b probs[b] * P[b,e] : in-lane over (mt,r), shfl over q, LDS over mg
    float sp[4];
#pragma unroll
    for (int ct = 0; ct < 4; ++ct) {
      float t = 0.f;
#pragma unroll
      for (int mt = 0; mt < MTW; ++mt) {
        float4 p4;
        if (iter == 0) { p4.x = invR; p4.y = invR; p4.z = invR; p4.w = invR; }
        else           { p4 = *(const float4*)&probs[mg * (R / 2) + mt * 16 + q * 4]; }
        t += p4.x * acc[mt][ct][0];
        t += p4.y * acc[mt][ct][1];
        t += p4.z * acc[mt][ct][2];
        t += p4.w * acc[mt][ct][3];
      }
      t += __shfl_xor(t, 16);
      t += __shfl_xor(t, 32);
      sp[ct] = t;
    }
    if (q == 0) {
#pragma unroll
      for (int ct = 0; ct < 4; ++ct) smat[mg][eg * 64 + ct * 16 + li] = sp[ct];
    }
    __syncthreads();
    float s[4];
#pragma unroll
    for (int ct = 0; ct < 4; ++ct) {
      int e = eg * 64 + ct * 16 + li;
      s[ct] = smat[0][e] + smat[1][e];
    }
    // squash
    float ss = s[0] * s[0] + s[1] * s[1] + s[2] * s[2] + s[3] * s[3];
    ss += __shfl_xor(ss, 1);
    ss += __shfl_xor(ss, 2);
    ss += __shfl_xor(ss, 4);
    ss += __shfl_xor(ss, 8);
    if (mg == 0 && lane == 0) sqpart[eg] = ss;
    __syncthreads();
    float sq = sqpart[0] + sqpart[1] + sqpart[2] + sqpart[3];
    float scale = (sq > 0.f) ? sq / ((1.0f + sq) * sqrtf(sq)) : 0.f;
#pragma unroll
    for (int ct = 0; ct < 4; ++ct) v[ct] = s[ct] * scale;

    if (iter < 2) {
      // logits[b] += sum_e P[b,e] * v[e] : in-lane over ct, shfl over li, LDS over eg
#pragma unroll
      for (int mt = 0; mt < MTW; ++mt) {
        float t0, t1, t2, t3;
        {
          float t = acc[mt][0][0] * v[0] + acc[mt][1][0] * v[1] +
                    acc[mt][2][0] * v[2] + acc[mt][3][0] * v[3];
          t += __shfl_xor(t, 1); t += __shfl_xor(t, 2);
          t += __shfl_xor(t, 4); t += __shfl_xor(t, 8);
          t0 = t;
        }
        {
          float t = acc[mt][0][1] * v[0] + acc[mt][1][1] * v[1] +
                    acc[mt][2][1] * v[2] + acc[mt][3][1] * v[3];
          t += __shfl_xor(t, 1); t += __shfl_xor(t, 2);
          t += __shfl_xor(t, 4); t += __shfl_xor(t, 8);
          t1 = t;
        }
        {
          float t = acc[mt][0][2] * v[0] + acc[mt][1][2] * v[1] +
                    acc[mt][2][2] * v[2] + acc[mt][3][2] * v[3];
          t += __shfl_xor(t, 1); t += __shfl_xor(t, 2);
          t += __shfl_xor(t, 4); t += __shfl_xor(t, 8);
          t2 = t;
        }
        {
          float t = acc[mt][0][3] * v[0] + acc[mt][1][3] * v[1] +
                    acc[mt][2][3] * v[2] + acc[mt][3][3] * v[3];
          t += __shfl_xor(t, 1); t += __shfl_xor(t, 2);
          t += __shfl_xor(t, 4); t += __shfl_xor(t, 8);
          t3 = t;
        }
        if (li == 0)
          *(float4*)&wlog[eg][mg * (R / 2) + mt * 16 + q * 4] = make_float4(t0, t1, t2, t3);
      }
      __syncthreads();
      if (tid < R) {
        float l = (iter == 0 ? 0.f : logits[tid]);
        l += wlog[0][tid] + wlog[1][tid] + wlog[2][tid] + wlog[3][tid];
        logits[tid] = l;
      }
      __syncthreads();
      if (w == 0) {  // softmax over R logits, wave 0
        float l0 = logits[lane];
        float l1 = (R == 128) ? logits[lane + 64] : -3.0e38f;
        float m = fmaxf(l0, l1);
#pragma unroll
        for (int d2 = 1; d2 < 64; d2 <<= 1) m = fmaxf(m, __shfl_xor(m, d2));
        float e0 = expf(l0 - m);
        float e1 = (R == 128) ? expf(l1 - m) : 0.f;
        float zz = e0 + e1;
#pragma unroll
        for (int d2 = 1; d2 < 64; d2 <<= 1) zz += __shfl_xor(zz, d2);
        float inv = 1.0f / zz;
        probs[lane] = e0 * inv;
        if (R == 128) probs[lane + 64] = e1 * inv;
      }
      __syncthreads();
    }
  }

  // ---- epilogue. stage1 -> split out1[a][kk][e]; stage2 -> fp32 out[kk][a][e] ----
  if (mg == 0 && q == 0) {
    if (stage == 1) {
      size_t ob = ((size_t)a * KN + kk) * 256;
#pragma unroll
      for (int ct = 0; ct < 4; ++ct) {
        int e = eg * 64 + ct * 16 + li;
        u32 hb = bf16_rne(v[ct]);
        u32 lb = bf16_rne(v[ct] - bf16_val(hb));
        o1hi[ob + e] = (u16)hb;
        o1lo[ob + e] = (u16)lb;
      }
    } else {
      size_t ob = ((size_t)kk * 64 + a) * 256;
#pragma unroll
      for (int ct = 0; ct < 4; ++ct) {
        int e = eg * 64 + ct * 16 + li;
        outp[ob + e] = v[ct];
      }
    }
  }
}

extern "C" void kernel_launch(void* const* d_in, const int* in_sizes, int n_in,
                              void* d_out, int out_size, void* d_ws, size_t ws_size,
                              hipStream_t stream) {
  const float* x  = (const float*)d_in[0];   // [64][128][256]
  const float* w1 = (const float*)d_in[1];   // [64][256][256]
  const float* wc = (const float*)d_in[2];   // [32][256][256]
  float* out = (float*)d_out;                // [32][64][256]

  char* ws = (char*)d_ws;
  u16* w1hi = (u16*)(ws);                    // 8 MB
  u16* w1lo = (u16*)(ws + (8u << 20));       // 8 MB
  u16* wchi = (u16*)(ws + (16u << 20));      // 4 MB
  u16* wclo = (u16*)(ws + (20u << 20));      // 4 MB
  u16* xhi  = (u16*)(ws + (24u << 20));      // 4 MB
  u16* xlo  = (u16*)(ws + (28u << 20));      // 4 MB
  u16* o1hi = (u16*)(ws + (32u << 20));      // 2 MB
  u16* o1lo = (u16*)(ws + (34u << 20));      // 2 MB

  split_arr<<<2048, 256, 0, stream>>>(x, xhi, xlo, 524288);
  split_transpose256<<<dim3(8, 8, 64), dim3(32, 8), 0, stream>>>(w1, w1hi, w1lo);
  split_transpose256<<<dim3(8, 8, 32), dim3(32, 8), 0, stream>>>(wc, wchi, wclo);
  caps_route<128><<<64 * 64, 512, 0, stream>>>(xhi, xlo, w1hi, w1lo, o1hi, o1lo, nullptr, 64, 1);
  caps_route<64><<<32 * 64, 512, 0, stream>>>(o1hi, o1lo, wchi, wclo, nullptr, nullptr, out, 32, 2);
}